// Round 1
// baseline (178.422 us; speedup 1.0000x reference)
//
#include <hip/hip_runtime.h>
#include <math.h>

// Burgers PINN: u = MLP(x,t) (2->10x7->1, tanh), outputs u, f, u_x, u_xx at 1M
// collocation points + plain forward at 3x16384 IC/boundary points.
// Forward-mode AD with 4 channels: (val, d/dx, d/dt, d2/dx2).
//
// R11: weights via LDS instead of SGPR s_load. Measured invariants (R5-R10):
// VALU issue ~17.3k cyc/wave (pk_fma_f32 is NOT double-rate; packed = code
// density only), VALUBusy capped ~78% at any occupancy -> idle is the
// per-layer SMEM drain: s_load returns are OUT-OF-ORDER so first weight use
// forces lgkmcnt(0) (full-layer latency, phase-correlated across waves), and
// the 112-SGPR budget (~110 SGPRs/layer) makes cross-layer prefetch
// impossible in SGPRs. Fix: stage all 811 weight floats in LDS once per
// block; ds_read returns IN-ORDER -> fine-grained lgkmcnt(N) waits, and the
// ~168 spare VGPRs let the scheduler hoist next-layer ds_reads into the
// current layer's tanh epilogue. Weight reads are wave-uniform -> broadcast,
// no bank conflicts.

#define NU_CONST 0.0031830988618379067f   // 0.01 / pi
#define TWO_OVER_LN2 2.8853900817779268f  // 2 / ln(2)

typedef float v2f __attribute__((ext_vector_type(2)));

__device__ __forceinline__ v2f splat2(float s) {
    v2f r; r.x = s; r.y = s; return r;
}
__device__ __forceinline__ v2f pk_fma(v2f a, v2f b, v2f c) {
    return __builtin_elementwise_fma(a, b, c);
}

__device__ __forceinline__ float fast_tanh(float x) {
    float e = __builtin_amdgcn_exp2f(x * TWO_OVER_LN2);
    float r = __builtin_amdgcn_rcpf(e + 1.0f);
    return fmaf(-2.0f, r, 1.0f);
}

// Packed tanh on a pair.
__device__ __forceinline__ v2f tanh2(v2f z2) {
    v2f a2 = z2 * splat2(TWO_OVER_LN2);
    v2f e2;
    e2.x = __builtin_amdgcn_exp2f(a2.x);
    e2.y = __builtin_amdgcn_exp2f(a2.y);
    v2f ep = e2 + splat2(1.0f);
    v2f r2;
    r2.x = __builtin_amdgcn_rcpf(ep.x);
    r2.y = __builtin_amdgcn_rcpf(ep.y);
    return pk_fma(splat2(-2.0f), r2, splat2(1.0f));
}

// One hidden 10->10 tanh layer, 4 AD channels, TWO points per thread.
// W/B point into LDS (wave-uniform broadcast reads, in-order returns).
// Each weight pair w2 is loaded once and feeds 8 pk_fmas.
__device__ __forceinline__ void hidden10_ad_x2(const float* W,
                                               const float* B,
                                               float h[2][10], float hx[2][10],
                                               float ht[2][10], float hxx[2][10]) {
    v2f Z[2][5], Zx[2][5], Zt[2][5], Zxx[2][5];
#pragma unroll
    for (int jp = 0; jp < 5; ++jp) {
        v2f w2 = *(const v2f*)(W + 2 * jp);   // row 0
        v2f b2 = *(const v2f*)(B + 2 * jp);
#pragma unroll
        for (int p = 0; p < 2; ++p) {
            Z[p][jp]   = pk_fma(splat2(h[p][0]), w2, b2);
            Zx[p][jp]  = splat2(hx[p][0]) * w2;
            Zt[p][jp]  = splat2(ht[p][0]) * w2;
            Zxx[p][jp] = splat2(hxx[p][0]) * w2;
        }
    }
#pragma unroll
    for (int i = 1; i < 10; ++i) {
#pragma unroll
        for (int jp = 0; jp < 5; ++jp) {
            v2f w2 = *(const v2f*)(W + i * 10 + 2 * jp);
#pragma unroll
            for (int p = 0; p < 2; ++p) {
                Z[p][jp]   = pk_fma(splat2(h[p][i]),   w2, Z[p][jp]);
                Zx[p][jp]  = pk_fma(splat2(hx[p][i]),  w2, Zx[p][jp]);
                Zt[p][jp]  = pk_fma(splat2(ht[p][i]),  w2, Zt[p][jp]);
                Zxx[p][jp] = pk_fma(splat2(hxx[p][i]), w2, Zxx[p][jp]);
            }
        }
    }
#pragma unroll
    for (int p = 0; p < 2; ++p) {
#pragma unroll
        for (int jp = 0; jp < 5; ++jp) {
            v2f v2v = tanh2(Z[p][jp]);
            v2f s2  = pk_fma(-v2v, v2v, splat2(1.0f));   // 1 - v^2
            v2f sx2 = s2 * Zx[p][jp];
            v2f m2v = splat2(-2.0f) * v2v;
            v2f htn2 = s2 * Zt[p][jp];
            // d2/dx2 tanh(z) = s*zxx + (-2v)*(sx*zx)
            v2f hxxn2 = pk_fma(s2, Zxx[p][jp], m2v * (sx2 * Zx[p][jp]));
            h[p][2*jp]   = v2v.x;   h[p][2*jp+1]   = v2v.y;
            hx[p][2*jp]  = sx2.x;   hx[p][2*jp+1]  = sx2.y;
            ht[p][2*jp]  = htn2.x;  ht[p][2*jp+1]  = htn2.y;
            hxx[p][2*jp] = hxxn2.x; hxx[p][2*jp+1] = hxxn2.y;
        }
    }
}

// Values-only hidden layer (boundary/IC points), packed over j-pairs.
__device__ __forceinline__ void hidden10_fwd(const float* W,
                                             const float* B,
                                             float h[10]) {
    v2f Z[5];
    {
        v2f hs = splat2(h[0]);
#pragma unroll
        for (int jp = 0; jp < 5; ++jp) {
            v2f w2 = *(const v2f*)(W + 2 * jp);
            v2f b2 = *(const v2f*)(B + 2 * jp);
            Z[jp] = pk_fma(hs, w2, b2);
        }
    }
#pragma unroll
    for (int i = 1; i < 10; ++i) {
        v2f hs = splat2(h[i]);
#pragma unroll
        for (int jp = 0; jp < 5; ++jp) {
            v2f w2 = *(const v2f*)(W + i * 10 + 2 * jp);
            Z[jp] = pk_fma(hs, w2, Z[jp]);
        }
    }
#pragma unroll
    for (int jp = 0; jp < 5; ++jp) {
        v2f v2v = tanh2(Z[jp]);
        h[2*jp] = v2v.x;
        h[2*jp+1] = v2v.y;
    }
}

// LDS weight layout (floats):
//   W1:0(20) b1:20(10) | for l in 0..6: W(l+2):30+110l(100) b(l+2):130+110l(10)
//   W9:800(10) b9:810(1)   -> total 811
__global__ __launch_bounds__(256)
__attribute__((amdgpu_waves_per_eu(2, 2)))
void pinn_fused_kernel(
    const float* __restrict__ Xf,
    const float* __restrict__ X0, const float* __restrict__ XL,
    const float* __restrict__ XR,
    const float* __restrict__ W1, const float* __restrict__ b1,
    const float* __restrict__ W2, const float* __restrict__ b2,
    const float* __restrict__ W3, const float* __restrict__ b3,
    const float* __restrict__ W4, const float* __restrict__ b4,
    const float* __restrict__ W5, const float* __restrict__ b5,
    const float* __restrict__ W6, const float* __restrict__ b6,
    const float* __restrict__ W7, const float* __restrict__ b7,
    const float* __restrict__ W8, const float* __restrict__ b8,
    const float* __restrict__ W9, const float* __restrict__ b9,
    float* __restrict__ out_u, float* __restrict__ out_f,
    float* __restrict__ out_ux, float* __restrict__ out_uxx,
    float* __restrict__ O0, float* __restrict__ OL, float* __restrict__ OR_,
    int n_colloc_blocks, int NF2, int N0) {
    __shared__ float wl[816];
    {
        int t = threadIdx.x;
        if (t < 30) wl[t] = (t < 20) ? W1[t] : b1[t - 20];
        const float* Wp[7] = {W2, W3, W4, W5, W6, W7, W8};
        const float* Bp[7] = {b2, b3, b4, b5, b6, b7, b8};
#pragma unroll
        for (int l = 0; l < 7; ++l) {
            if (t < 100)       wl[30 + 110 * l + t] = Wp[l][t];
            else if (t < 110)  wl[30 + 110 * l + t] = Bp[l][t - 100];
        }
        if (t < 10)       wl[800 + t] = W9[t];
        else if (t == 10) wl[810] = b9[0];
        __syncthreads();
    }
    const float* Lw1 = wl;        const float* Lb1 = wl + 20;
    const float* Lw9 = wl + 800;  const float  Lb9 = wl[810];

    if ((int)blockIdx.x < n_colloc_blocks) {
        // ------------- collocation path: 2 points, 4 AD channels -------------
        int gid = blockIdx.x * blockDim.x + threadIdx.x;   // pair index
        if (gid >= NF2) return;
        // Points 2*gid and 2*gid+1: one float4 = (x0,t0,x1,t1).
        float4 xt2 = ((const float4*)Xf)[gid];
        float xin[2], tin[2];
        xin[0] = xt2.x; tin[0] = xt2.y;
        xin[1] = xt2.z; tin[1] = xt2.w;

        float h[2][10], hx[2][10], ht[2][10], hxx[2][10];
        // Layer 1: 2 -> 10, tanh. Seeds: dx=(1,0), dt=(0,1), dxx=0.
#pragma unroll
        for (int jp = 0; jp < 5; ++jp) {
            v2f wx2 = *(const v2f*)(Lw1 + 2 * jp);        // W1 row 0
            v2f wt2 = *(const v2f*)(Lw1 + 10 + 2 * jp);   // W1 row 1
            v2f b2  = *(const v2f*)(Lb1 + 2 * jp);
#pragma unroll
            for (int p = 0; p < 2; ++p) {
                v2f z2  = pk_fma(splat2(xin[p]), wx2,
                                 pk_fma(splat2(tin[p]), wt2, b2));
                v2f v2v = tanh2(z2);
                v2f s2  = pk_fma(-v2v, v2v, splat2(1.0f));
                v2f sx2 = s2 * wx2;
                v2f m2v = splat2(-2.0f) * v2v;
                v2f st2 = s2 * wt2;
                v2f sxx2 = m2v * (sx2 * wx2);   // zxx = 0 at layer 1
                h[p][2*jp]   = v2v.x;  h[p][2*jp+1]   = v2v.y;
                hx[p][2*jp]  = sx2.x;  hx[p][2*jp+1]  = sx2.y;
                ht[p][2*jp]  = st2.x;  ht[p][2*jp+1]  = st2.y;
                hxx[p][2*jp] = sxx2.x; hxx[p][2*jp+1] = sxx2.y;
            }
        }

        hidden10_ad_x2(wl + 30,  wl + 130, h, hx, ht, hxx);   // L2
        hidden10_ad_x2(wl + 140, wl + 240, h, hx, ht, hxx);   // L3
        hidden10_ad_x2(wl + 250, wl + 350, h, hx, ht, hxx);   // L4
        hidden10_ad_x2(wl + 360, wl + 460, h, hx, ht, hxx);   // L5
        hidden10_ad_x2(wl + 470, wl + 570, h, hx, ht, hxx);   // L6
        hidden10_ad_x2(wl + 580, wl + 680, h, hx, ht, hxx);   // L7
        hidden10_ad_x2(wl + 690, wl + 790, h, hx, ht, hxx);   // L8

        // Layer 9: 10 -> 1, linear. Packed pairwise dot + horizontal add.
        float u[2], ux[2], ut[2], uxx[2];
#pragma unroll
        for (int p = 0; p < 2; ++p) {
            v2f w0 = *(const v2f*)(Lw9);
            v2f hu, hxu, htu, hxxu;
            hu.x   = h[p][0];   hu.y   = h[p][1];
            hxu.x  = hx[p][0];  hxu.y  = hx[p][1];
            htu.x  = ht[p][0];  htu.y  = ht[p][1];
            hxxu.x = hxx[p][0]; hxxu.y = hxx[p][1];
            v2f su   = hu   * w0;
            v2f sux  = hxu  * w0;
            v2f sut  = htu  * w0;
            v2f suxx = hxxu * w0;
#pragma unroll
            for (int jp = 1; jp < 5; ++jp) {
                v2f w2 = *(const v2f*)(Lw9 + 2 * jp);
                v2f a, b, c, d;
                a.x = h[p][2*jp];   a.y = h[p][2*jp+1];
                b.x = hx[p][2*jp];  b.y = hx[p][2*jp+1];
                c.x = ht[p][2*jp];  c.y = ht[p][2*jp+1];
                d.x = hxx[p][2*jp]; d.y = hxx[p][2*jp+1];
                su   = pk_fma(a, w2, su);
                sux  = pk_fma(b, w2, sux);
                sut  = pk_fma(c, w2, sut);
                suxx = pk_fma(d, w2, suxx);
            }
            u[p]   = Lb9 + (su.x + su.y);
            ux[p]  = sux.x + sux.y;
            ut[p]  = sut.x + sut.y;
            uxx[p] = suxx.x + suxx.y;
        }

        float2 st;
        st.x = u[0]; st.y = u[1];
        ((float2*)out_u)[gid] = st;
        st.x = ux[0]; st.y = ux[1];
        ((float2*)out_ux)[gid] = st;
        st.x = uxx[0]; st.y = uxx[1];
        ((float2*)out_uxx)[gid] = st;
        st.x = fmaf(u[0], ux[0], ut[0]) - NU_CONST * uxx[0];
        st.y = fmaf(u[1], ux[1], ut[1]) - NU_CONST * uxx[1];
        ((float2*)out_f)[gid] = st;   // u_t + u*u_x - nu*u_xx
    } else {
        // ---------------- forward-only path: IC + boundaries ----------------
        int idx = (blockIdx.x - n_colloc_blocks) * blockDim.x + threadIdx.x;
        if (idx >= 3 * N0) return;
        const float* X;
        float* O;
        int k;
        if (idx < N0)            { X = X0; O = O0;  k = idx; }
        else if (idx < 2 * N0)   { X = XL; O = OL;  k = idx - N0; }
        else                     { X = XR; O = OR_; k = idx - 2 * N0; }

        float2 xt = ((const float2*)X)[k];
        float x = xt.x;
        float t = xt.y;

        float h[10];
#pragma unroll
        for (int j = 0; j < 10; ++j) {
            float z = fmaf(x, wl[j], fmaf(t, wl[10 + j], wl[20 + j]));
            h[j] = fast_tanh(z);
        }
        hidden10_fwd(wl + 30,  wl + 130, h);
        hidden10_fwd(wl + 140, wl + 240, h);
        hidden10_fwd(wl + 250, wl + 350, h);
        hidden10_fwd(wl + 360, wl + 460, h);
        hidden10_fwd(wl + 470, wl + 570, h);
        hidden10_fwd(wl + 580, wl + 680, h);
        hidden10_fwd(wl + 690, wl + 790, h);

        float u = Lb9;
#pragma unroll
        for (int i = 0; i < 10; ++i) u = fmaf(h[i], Lw9[i], u);
        O[k] = u;
    }
}

extern "C" void kernel_launch(void* const* d_in, const int* in_sizes, int n_in,
                              void* d_out, int out_size, void* d_ws, size_t ws_size,
                              hipStream_t stream) {
    const float* Xf = (const float*)d_in[0];
    const float* X0 = (const float*)d_in[1];
    const float* XL = (const float*)d_in[2];
    const float* XR = (const float*)d_in[3];
    const float* W[9];
    const float* B[9];
    for (int i = 0; i < 9; ++i) {
        W[i] = (const float*)d_in[4 + 2 * i];
        B[i] = (const float*)d_in[5 + 2 * i];
    }
    int NF = in_sizes[0] / 2;
    int N0 = in_sizes[1] / 2;
    int NB = in_sizes[2] / 2;
    int NF2 = NF / 2;   // pairs of points (NF = 1048576, even)

    float* out = (float*)d_out;
    float* out_u   = out;                         // u_pred_f      [NF]
    float* out_0   = out + NF;                    // u_pred_0      [N0]
    float* out_bl  = out + NF + N0;               // u_pred_b_left [NB]
    float* out_br  = out + NF + N0 + NB;          // u_pred_b_right[NB]
    float* out_f   = out + NF + N0 + 2 * NB;      // f             [NF]
    float* out_ux  = out_f + NF;                  // u_x           [NF]
    float* out_uxx = out_ux + NF;                 // u_xx          [NF]

    int n_colloc_blocks = (NF2 + 255) / 256;
    int n_fwd_blocks    = (3 * N0 + 255) / 256;
    dim3 blk(256);
    dim3 grd(n_colloc_blocks + n_fwd_blocks);
    pinn_fused_kernel<<<grd, blk, 0, stream>>>(
        Xf, X0, XL, XR,
        W[0], B[0], W[1], B[1], W[2], B[2], W[3], B[3], W[4], B[4],
        W[5], B[5], W[6], B[6], W[7], B[7], W[8], B[8],
        out_u, out_f, out_ux, out_uxx,
        out_0, out_bl, out_br,
        n_colloc_blocks, NF2, N0);
}

// Round 2
// 175.306 us; speedup vs baseline: 1.0178x; 1.0178x over previous
//
#include <hip/hip_runtime.h>
#include <math.h>

// Burgers PINN: u = MLP(x,t) (2->10x7->1, tanh), outputs u, f, u_x, u_xx at 1M
// collocation points + plain forward at 3x16384 IC/boundary points.
// Forward-mode AD with 4 channels: (val, d/dx, d/dt, d2/dx2).
//
// R12: ROLLED hidden layers (I-fetch theory). Evidence: VALUBusy caps ~78%
// at ANY occupancy 1.7-4.4 w/SIMD (R5-R9) -> the idle is a per-CU shared
// resource scaling with the instruction stream, i.e. instruction fetch:
// fully-unrolled kernel is ~50 KB straight-line code > 32 KB L1I, streamed
// once per wave with zero reuse. R11 corroborates: LDS-weights version made
// the body BIGGER and VALUBusy fell 77->70 (busy moves inversely with code
// size). Fix: pack hidden-layer weights contiguously into d_ws (tiny packer
// kernel), then run layers 2-8 as a real loop (unroll-disabled) over a
// marching uniform pointer (one SGPR pair + immediate-offset s_loads).
// Body ~4 KB -> whole kernel fits in L1I. Accepted cost: one lgkmcnt(0)
// K$ latency per layer iteration (~1k cyc/wave total).
// s_load weights (NOT LDS: R11 showed ds_read latency in-loop is worse).

#define NU_CONST 0.0031830988618379067f   // 0.01 / pi
#define TWO_OVER_LN2 2.8853900817779268f  // 2 / ln(2)

typedef float v2f __attribute__((ext_vector_type(2)));

__device__ __forceinline__ v2f splat2(float s) {
    v2f r; r.x = s; r.y = s; return r;
}
__device__ __forceinline__ v2f pk_fma(v2f a, v2f b, v2f c) {
    return __builtin_elementwise_fma(a, b, c);
}

__device__ __forceinline__ float fast_tanh(float x) {
    float e = __builtin_amdgcn_exp2f(x * TWO_OVER_LN2);
    float r = __builtin_amdgcn_rcpf(e + 1.0f);
    return fmaf(-2.0f, r, 1.0f);
}

// Packed tanh on a pair.
__device__ __forceinline__ v2f tanh2(v2f z2) {
    v2f a2 = z2 * splat2(TWO_OVER_LN2);
    v2f e2;
    e2.x = __builtin_amdgcn_exp2f(a2.x);
    e2.y = __builtin_amdgcn_exp2f(a2.y);
    v2f ep = e2 + splat2(1.0f);
    v2f r2;
    r2.x = __builtin_amdgcn_rcpf(ep.x);
    r2.y = __builtin_amdgcn_rcpf(ep.y);
    return pk_fma(splat2(-2.0f), r2, splat2(1.0f));
}

// One hidden 10->10 tanh layer, 4 AD channels, TWO points per thread.
// W/B are wave-uniform global pointers -> s_load_dwordx2 with immediate
// offsets off one SGPR base pair. Each weight pair feeds 8 pk_fmas.
__device__ __forceinline__ void hidden10_ad_x2(const float* __restrict__ W,
                                               const float* __restrict__ B,
                                               float h[2][10], float hx[2][10],
                                               float ht[2][10], float hxx[2][10]) {
    v2f Z[2][5], Zx[2][5], Zt[2][5], Zxx[2][5];
#pragma unroll
    for (int jp = 0; jp < 5; ++jp) {
        v2f w2 = *(const v2f*)(W + 2 * jp);   // row 0
        v2f b2 = *(const v2f*)(B + 2 * jp);
#pragma unroll
        for (int p = 0; p < 2; ++p) {
            Z[p][jp]   = pk_fma(splat2(h[p][0]), w2, b2);
            Zx[p][jp]  = splat2(hx[p][0]) * w2;
            Zt[p][jp]  = splat2(ht[p][0]) * w2;
            Zxx[p][jp] = splat2(hxx[p][0]) * w2;
        }
    }
#pragma unroll
    for (int i = 1; i < 10; ++i) {
#pragma unroll
        for (int jp = 0; jp < 5; ++jp) {
            v2f w2 = *(const v2f*)(W + i * 10 + 2 * jp);
#pragma unroll
            for (int p = 0; p < 2; ++p) {
                Z[p][jp]   = pk_fma(splat2(h[p][i]),   w2, Z[p][jp]);
                Zx[p][jp]  = pk_fma(splat2(hx[p][i]),  w2, Zx[p][jp]);
                Zt[p][jp]  = pk_fma(splat2(ht[p][i]),  w2, Zt[p][jp]);
                Zxx[p][jp] = pk_fma(splat2(hxx[p][i]), w2, Zxx[p][jp]);
            }
        }
    }
#pragma unroll
    for (int p = 0; p < 2; ++p) {
#pragma unroll
        for (int jp = 0; jp < 5; ++jp) {
            v2f v2v = tanh2(Z[p][jp]);
            v2f s2  = pk_fma(-v2v, v2v, splat2(1.0f));   // 1 - v^2
            v2f sx2 = s2 * Zx[p][jp];
            v2f m2v = splat2(-2.0f) * v2v;
            v2f htn2 = s2 * Zt[p][jp];
            // d2/dx2 tanh(z) = s*zxx + (-2v)*(sx*zx)
            v2f hxxn2 = pk_fma(s2, Zxx[p][jp], m2v * (sx2 * Zx[p][jp]));
            h[p][2*jp]   = v2v.x;   h[p][2*jp+1]   = v2v.y;
            hx[p][2*jp]  = sx2.x;   hx[p][2*jp+1]  = sx2.y;
            ht[p][2*jp]  = htn2.x;  ht[p][2*jp+1]  = htn2.y;
            hxx[p][2*jp] = hxxn2.x; hxx[p][2*jp+1] = hxxn2.y;
        }
    }
}

// Values-only hidden layer (boundary/IC points), packed over j-pairs.
__device__ __forceinline__ void hidden10_fwd(const float* __restrict__ W,
                                             const float* __restrict__ B,
                                             float h[10]) {
    v2f Z[5];
    {
        v2f hs = splat2(h[0]);
#pragma unroll
        for (int jp = 0; jp < 5; ++jp) {
            v2f w2 = *(const v2f*)(W + 2 * jp);
            v2f b2 = *(const v2f*)(B + 2 * jp);
            Z[jp] = pk_fma(hs, w2, b2);
        }
    }
#pragma unroll
    for (int i = 1; i < 10; ++i) {
        v2f hs = splat2(h[i]);
#pragma unroll
        for (int jp = 0; jp < 5; ++jp) {
            v2f w2 = *(const v2f*)(W + i * 10 + 2 * jp);
            Z[jp] = pk_fma(hs, w2, Z[jp]);
        }
    }
#pragma unroll
    for (int jp = 0; jp < 5; ++jp) {
        v2f v2v = tanh2(Z[jp]);
        h[2*jp] = v2v.x;
        h[2*jp+1] = v2v.y;
    }
}

// Pack hidden-layer weights contiguously: ws[110*l + 0..99] = W(l+2),
// ws[110*l + 100..109] = b(l+2), l = 0..6. 770 floats = 3080 B.
__global__ void pack_weights(
    const float* __restrict__ W2, const float* __restrict__ b2,
    const float* __restrict__ W3, const float* __restrict__ b3,
    const float* __restrict__ W4, const float* __restrict__ b4,
    const float* __restrict__ W5, const float* __restrict__ b5,
    const float* __restrict__ W6, const float* __restrict__ b6,
    const float* __restrict__ W7, const float* __restrict__ b7,
    const float* __restrict__ W8, const float* __restrict__ b8,
    float* __restrict__ ws) {
    int t = threadIdx.x;
    const float* Wp[7] = {W2, W3, W4, W5, W6, W7, W8};
    const float* Bp[7] = {b2, b3, b4, b5, b6, b7, b8};
#pragma unroll
    for (int l = 0; l < 7; ++l) {
        if (t < 100)      ws[110 * l + t] = Wp[l][t];
        else if (t < 110) ws[110 * l + t] = Bp[l][t - 100];
    }
}

__global__ __launch_bounds__(256)
__attribute__((amdgpu_waves_per_eu(2, 2)))
void pinn_fused_kernel(
    const float* __restrict__ Xf,
    const float* __restrict__ X0, const float* __restrict__ XL,
    const float* __restrict__ XR,
    const float* __restrict__ W1, const float* __restrict__ b1,
    const float* __restrict__ Wh,   // packed layers 2..8 in d_ws
    const float* __restrict__ W9, const float* __restrict__ b9,
    float* __restrict__ out_u, float* __restrict__ out_f,
    float* __restrict__ out_ux, float* __restrict__ out_uxx,
    float* __restrict__ O0, float* __restrict__ OL, float* __restrict__ OR_,
    int n_colloc_blocks, int NF2, int N0) {
    if ((int)blockIdx.x < n_colloc_blocks) {
        // ------------- collocation path: 2 points, 4 AD channels -------------
        int gid = blockIdx.x * blockDim.x + threadIdx.x;   // pair index
        if (gid >= NF2) return;
        // Points 2*gid and 2*gid+1: one float4 = (x0,t0,x1,t1).
        float4 xt2 = ((const float4*)Xf)[gid];
        float xin[2], tin[2];
        xin[0] = xt2.x; tin[0] = xt2.y;
        xin[1] = xt2.z; tin[1] = xt2.w;

        float h[2][10], hx[2][10], ht[2][10], hxx[2][10];
        // Layer 1: 2 -> 10, tanh. Seeds: dx=(1,0), dt=(0,1), dxx=0.
#pragma unroll
        for (int jp = 0; jp < 5; ++jp) {
            v2f wx2 = *(const v2f*)(W1 + 2 * jp);        // W1 row 0
            v2f wt2 = *(const v2f*)(W1 + 10 + 2 * jp);   // W1 row 1
            v2f b2  = *(const v2f*)(b1 + 2 * jp);
#pragma unroll
            for (int p = 0; p < 2; ++p) {
                v2f z2  = pk_fma(splat2(xin[p]), wx2,
                                 pk_fma(splat2(tin[p]), wt2, b2));
                v2f v2v = tanh2(z2);
                v2f s2  = pk_fma(-v2v, v2v, splat2(1.0f));
                v2f sx2 = s2 * wx2;
                v2f m2v = splat2(-2.0f) * v2v;
                v2f st2 = s2 * wt2;
                v2f sxx2 = m2v * (sx2 * wx2);   // zxx = 0 at layer 1
                h[p][2*jp]   = v2v.x;  h[p][2*jp+1]   = v2v.y;
                hx[p][2*jp]  = sx2.x;  hx[p][2*jp+1]  = sx2.y;
                ht[p][2*jp]  = st2.x;  ht[p][2*jp+1]  = st2.y;
                hxx[p][2*jp] = sxx2.x; hxx[p][2*jp+1] = sxx2.y;
            }
        }

        // Layers 2..8: ROLLED. One ~4 KB body, marching SGPR base pointer.
        {
            const float* Wl = Wh;
#pragma clang loop unroll(disable)
            for (int l = 0; l < 7; ++l) {
                hidden10_ad_x2(Wl, Wl + 100, h, hx, ht, hxx);
                Wl += 110;
            }
        }

        // Layer 9: 10 -> 1, linear. Packed pairwise dot + horizontal add.
        float u[2], ux[2], ut[2], uxx[2];
#pragma unroll
        for (int p = 0; p < 2; ++p) {
            v2f w0 = *(const v2f*)(W9);
            v2f hu, hxu, htu, hxxu;
            hu.x   = h[p][0];   hu.y   = h[p][1];
            hxu.x  = hx[p][0];  hxu.y  = hx[p][1];
            htu.x  = ht[p][0];  htu.y  = ht[p][1];
            hxxu.x = hxx[p][0]; hxxu.y = hxx[p][1];
            v2f su   = hu   * w0;
            v2f sux  = hxu  * w0;
            v2f sut  = htu  * w0;
            v2f suxx = hxxu * w0;
#pragma unroll
            for (int jp = 1; jp < 5; ++jp) {
                v2f w2 = *(const v2f*)(W9 + 2 * jp);
                v2f a, b, c, d;
                a.x = h[p][2*jp];   a.y = h[p][2*jp+1];
                b.x = hx[p][2*jp];  b.y = hx[p][2*jp+1];
                c.x = ht[p][2*jp];  c.y = ht[p][2*jp+1];
                d.x = hxx[p][2*jp]; d.y = hxx[p][2*jp+1];
                su   = pk_fma(a, w2, su);
                sux  = pk_fma(b, w2, sux);
                sut  = pk_fma(c, w2, sut);
                suxx = pk_fma(d, w2, suxx);
            }
            u[p]   = b9[0] + (su.x + su.y);
            ux[p]  = sux.x + sux.y;
            ut[p]  = sut.x + sut.y;
            uxx[p] = suxx.x + suxx.y;
        }

        float2 st;
        st.x = u[0]; st.y = u[1];
        ((float2*)out_u)[gid] = st;
        st.x = ux[0]; st.y = ux[1];
        ((float2*)out_ux)[gid] = st;
        st.x = uxx[0]; st.y = uxx[1];
        ((float2*)out_uxx)[gid] = st;
        st.x = fmaf(u[0], ux[0], ut[0]) - NU_CONST * uxx[0];
        st.y = fmaf(u[1], ux[1], ut[1]) - NU_CONST * uxx[1];
        ((float2*)out_f)[gid] = st;   // u_t + u*u_x - nu*u_xx
    } else {
        // ---------------- forward-only path: IC + boundaries ----------------
        int idx = (blockIdx.x - n_colloc_blocks) * blockDim.x + threadIdx.x;
        if (idx >= 3 * N0) return;
        const float* X;
        float* O;
        int k;
        if (idx < N0)            { X = X0; O = O0;  k = idx; }
        else if (idx < 2 * N0)   { X = XL; O = OL;  k = idx - N0; }
        else                     { X = XR; O = OR_; k = idx - 2 * N0; }

        float2 xt = ((const float2*)X)[k];
        float x = xt.x;
        float t = xt.y;

        float h[10];
#pragma unroll
        for (int j = 0; j < 10; ++j) {
            float z = fmaf(x, W1[j], fmaf(t, W1[10 + j], b1[j]));
            h[j] = fast_tanh(z);
        }
        {
            const float* Wl = Wh;
#pragma clang loop unroll(disable)
            for (int l = 0; l < 7; ++l) {
                hidden10_fwd(Wl, Wl + 100, h);
                Wl += 110;
            }
        }

        float u = b9[0];
#pragma unroll
        for (int i = 0; i < 10; ++i) u = fmaf(h[i], W9[i], u);
        O[k] = u;
    }
}

extern "C" void kernel_launch(void* const* d_in, const int* in_sizes, int n_in,
                              void* d_out, int out_size, void* d_ws, size_t ws_size,
                              hipStream_t stream) {
    const float* Xf = (const float*)d_in[0];
    const float* X0 = (const float*)d_in[1];
    const float* XL = (const float*)d_in[2];
    const float* XR = (const float*)d_in[3];
    const float* W[9];
    const float* B[9];
    for (int i = 0; i < 9; ++i) {
        W[i] = (const float*)d_in[4 + 2 * i];
        B[i] = (const float*)d_in[5 + 2 * i];
    }
    int NF = in_sizes[0] / 2;
    int N0 = in_sizes[1] / 2;
    int NB = in_sizes[2] / 2;
    int NF2 = NF / 2;   // pairs of points (NF = 1048576, even)

    float* out = (float*)d_out;
    float* out_u   = out;                         // u_pred_f      [NF]
    float* out_0   = out + NF;                    // u_pred_0      [N0]
    float* out_bl  = out + NF + N0;               // u_pred_b_left [NB]
    float* out_br  = out + NF + N0 + NB;          // u_pred_b_right[NB]
    float* out_f   = out + NF + N0 + 2 * NB;      // f             [NF]
    float* out_ux  = out_f + NF;                  // u_x           [NF]
    float* out_uxx = out_ux + NF;                 // u_xx          [NF]

    float* wpack = (float*)d_ws;                  // 770 floats = 3080 B
    pack_weights<<<dim3(1), dim3(128), 0, stream>>>(
        W[1], B[1], W[2], B[2], W[3], B[3], W[4], B[4],
        W[5], B[5], W[6], B[6], W[7], B[7], wpack);

    int n_colloc_blocks = (NF2 + 255) / 256;
    int n_fwd_blocks    = (3 * N0 + 255) / 256;
    dim3 blk(256);
    dim3 grd(n_colloc_blocks + n_fwd_blocks);
    pinn_fused_kernel<<<grd, blk, 0, stream>>>(
        Xf, X0, XL, XR,
        W[0], B[0], wpack, W[8], B[8],
        out_u, out_f, out_ux, out_uxx,
        out_0, out_bl, out_br,
        n_colloc_blocks, NF2, N0);
}